// Round 15
// baseline (301.731 us; speedup 1.0000x reference)
//
#include <hip/hip_runtime.h>
#include <hip/hip_bf16.h>
#include <stdint.h>

#define L 49
#define C 128
#define H 32
#define NPERS 768   // persistent grid: 3 blocks/CU x 256 CUs

typedef __attribute__((ext_vector_type(8))) short bf16x8;
typedef __attribute__((ext_vector_type(4))) float f32x4;

// LDS pitches (elements)
#define XP 136    // x staging pitch (bf16), inside s_xv region
#define VTP 72    // V^T pitch: 144B rows (16B-aligned, 36 dw = 4 mod 32 -> 2-way max)
#define QKP 264   // Q|K pitch: 528B rows (16B-aligned, 132 dw = 4 mod 32 -> 2-way max)

#define LOG2E 1.44269504f

// round-half-up f32->bf16 bit helpers (1 VALU op each) — known-good path
__device__ __forceinline__ uint32_t rbits(float f) {
  return __builtin_bit_cast(uint32_t, f) + 0x8000u;
}
// pack bf16(a) into low u16, bf16(b) into high u16 (one v_perm_b32)
__device__ __forceinline__ uint32_t pack2(float a, float b) {
  return __builtin_amdgcn_perm(rbits(b), rbits(a), 0x07060302u);
}
__device__ __forceinline__ ushort bf1(float a) { return (ushort)(rbits(a) >> 16); }

__device__ __forceinline__ bf16x8 mk_frag(uint2 d, bool valid) {
  union { uint32_t u[4]; bf16x8 v; } r;
  r.u[0] = valid ? d.x : 0u;
  r.u[1] = valid ? d.y : 0u;
  r.u[2] = 0u; r.u[3] = 0u;
  return r.v;
}
__device__ __forceinline__ bf16x8 zero8() {
  union { uint32_t u[4]; bf16x8 v; } r;
  r.u[0] = r.u[1] = r.u[2] = r.u[3] = 0u;
  return r.v;
}
__device__ __forceinline__ bf16x8 ones8() {   // 8 x bf16(1.0)
  union { uint32_t u[4]; bf16x8 v; } r;
  r.u[0] = r.u[1] = r.u[2] = r.u[3] = 0x3F803F80u;
  return r.v;
}

// ---- prep 1: transpose+convert weights to bf16 ----
__global__ void __launch_bounds__(256) prep_weights_kernel(
    const float* __restrict__ Wqkv, const float* __restrict__ Wproj,
    ushort* __restrict__ ws) {
  int i = blockIdx.x * 256 + threadIdx.x;
  if (i < 384 * 128) {
    int n = i >> 7, k = i & 127;
    ws[i] = bf1(Wqkv[k * 384 + n]);            // W_qkvT[n][k]
  } else {
    int j = i - 384 * 128;
    if (j < 128 * 128) {
      int n = j >> 7, k = j & 127;
      ws[49152 + j] = bf1(Wproj[k * 128 + n]); // W_projT[n][k]
    }
  }
}

// ---- prep 2: expand bias (pre-scaled by log2e) into MFMA C-frag layout ----
__global__ void __launch_bounds__(256) prep_bias_kernel(
    const float* __restrict__ bt, float* __restrict__ biasx) {
  int i = blockIdx.x * 256 + threadIdx.x;   // 131072 total
  int r = i & 3, lane = (i >> 2) & 63, t = i >> 8;
  int nt = t & 3, mt = (t >> 2) & 3, h = t >> 4;
  int q = nt * 16 + (lane & 15);
  int k = mt * 16 + ((lane >> 4) & 3) * 4 + r;
  float v = -1e30f;
  if (q < L && k < L) {
    int qi = q / 7, qj = q % 7, ki = k / 7, kj = k % 7;
    int idx = (qi - ki + 6) * 13 + (qj - kj + 6);
    v = bt[idx * H + h] * LOG2E;               // log2-domain bias
  }
  biasx[i] = v;
}

// per-head attention body: QK^T MFMA (C preloaded with bias), exp2 softmax,
// P->LDS bf16 swizzled, PV MFMA with ones-channel denominator, O write.
__device__ __forceinline__ void head_body(
    f32x4 (&acc)[4][4], int h, const ushort* qk, const ushort* vt,
    char* pw, ushort* qk_mut, int lr, int lg) {
  bf16x8 ka[4], qb[4];
  #pragma unroll
  for (int mt = 0; mt < 4; ++mt) {
    int row = mt * 16 + lr; if (row > 48) row = 48;
    uint2 d = *(const uint2*)&qk[row * QKP + 128 + h * 4];
    ka[mt] = mk_frag(d, lg == 0);
  }
  #pragma unroll
  for (int nt = 0; nt < 4; ++nt) {
    int row = nt * 16 + lr; if (row > 48) row = 48;
    uint2 d = *(const uint2*)&qk[row * QKP + h * 4];
    qb[nt] = mk_frag(d, lg == 0);
  }
  __builtin_amdgcn_s_setprio(1);
  #pragma unroll
  for (int nt = 0; nt < 4; ++nt)
    #pragma unroll
    for (int mt = 0; mt < 4; ++mt)
      acc[mt][nt] = __builtin_amdgcn_mfma_f32_16x16x32_bf16(ka[mt], qb[nt], acc[mt][nt], 0, 0, 0);
  __builtin_amdgcn_s_setprio(0);
  bf16x8 va[2];
  #pragma unroll
  for (int ks = 0; ks < 2; ++ks) {
    bf16x8 t = *(const bf16x8*)&vt[(h * 4 + (lr & 3)) * VTP + ks * 32 + lg * 8];
    va[ks] = (lr < 4) ? t : ((lr == 4) ? ones8() : zero8());
  }
  // mt==3 trim: r>0 k-slots are always pad -> exp2 = 0 -> constant bits.
  #pragma unroll
  for (int nt = 0; nt < 4; ++nt) {
    #pragma unroll
    for (int mt = 0; mt < 4; ++mt) {
      uint32_t d0, d1;
      if (mt < 3) {
        uint32_t u0 = rbits(__builtin_amdgcn_exp2f(acc[mt][nt][0]));
        uint32_t u1 = rbits(__builtin_amdgcn_exp2f(acc[mt][nt][1]));
        uint32_t u2 = rbits(__builtin_amdgcn_exp2f(acc[mt][nt][2]));
        uint32_t u3 = rbits(__builtin_amdgcn_exp2f(acc[mt][nt][3]));
        d0 = __builtin_amdgcn_perm(u1, u0, 0x07060302u);
        d1 = __builtin_amdgcn_perm(u3, u2, 0x07060302u);
      } else {
        float e0 = __builtin_amdgcn_exp2f(acc[mt][nt][0]);  // k=48 (valid for lg==0)
        d0 = pack2(e0, 0.0f);
        d1 = 0u;
      }
      int byte = lr * 128 + mt * 32 + lg * 8;
      byte ^= (lr & 7) << 4;
      *(uint2*)(pw + byte) = make_uint2(d0, d1);
    }
    f32x4 oo = {0.f, 0.f, 0.f, 0.f};
    __builtin_amdgcn_s_setprio(1);
    #pragma unroll
    for (int ks = 0; ks < 2; ++ks) {
      int byte = lr * 128 + ks * 64 + lg * 16;
      byte ^= (lr & 7) << 4;
      bf16x8 pb = *(const bf16x8*)(pw + byte);
      oo = __builtin_amdgcn_mfma_f32_16x16x32_bf16(va[ks], pb, oo, 0, 0, 0);
    }
    __builtin_amdgcn_s_setprio(0);
    float den = __shfl_xor(oo[0], 16);
    if (lg == 0) {
      float iv = __builtin_amdgcn_rcpf(den);
      int q = nt * 16 + lr;
      if (q < L) {
        uint2 od = make_uint2(pack2(oo[0] * iv, oo[1] * iv),
                              pack2(oo[2] * iv, oo[3] * iv));
        *(uint2*)&qk_mut[q * QKP + h * 4] = od;
      }
    }
  }
}

// PERSISTENT blocks: grid = min(bn, 768) = 3/CU; each block loops over windows
// w, w+NPERS, ... . Next window's x is loaded into registers right after the
// current window's x-regs are consumed -> HBM latency hides under P1/P2/P3.
__global__ void __launch_bounds__(256, 3) win_attn_kernel(
    const float* __restrict__ x,
    const float* __restrict__ b_qkv,
    const float* __restrict__ b_proj,
    const ushort* __restrict__ wqkvT,
    const ushort* __restrict__ wprojT,
    const float* __restrict__ biasx,
    float* __restrict__ out,
    int bn, int npers) {
  __shared__ alignas(16) ushort s_xv[C * VTP];       // 18432 B: x staging / V^T alias
  __shared__ alignas(16) ushort qk[L * QKP];         // 25872 B: Q(0:128)|K(128:256)
  __shared__ alignas(16) ushort p_lds[4][16 * 64];   //  8192 B: per-wave P, XOR-swizzled
  // total 52496 B -> 3 blocks/CU

  ushort* xa = s_xv;   // pitch XP (x staging)
  ushort* vt = s_xv;   // pitch VTP (V^T)

  const int tid = threadIdx.x;
  const int wv = tid >> 6;
  const int l = tid & 63;
  const int lr = l & 15;
  const int lg = l >> 4;

  // ---- prologue: load first window's x into registers ----
  float4 xr[7];
  int w = blockIdx.x;
  {
    const float4* xv = (const float4*)(x + (size_t)w * (L * C));
    #pragma unroll
    for (int j = 0; j < 7; ++j) {
      int i = tid + j * 256;
      if (i < L * C / 4) xr[j] = xv[i];
    }
  }

  for (; w < bn; ) {
    // ---- P0': pack x regs -> LDS ----
    #pragma unroll
    for (int j = 0; j < 7; ++j) {
      int i = tid + j * 256;
      if (i < L * C / 4) {
        float4 v = xr[j];
        int e = i * 4;
        int r = e >> 7, c = e & 127;
        *(uint2*)&xa[r * XP + c] = make_uint2(pack2(v.x, v.y), pack2(v.z, v.w));
      }
    }
    // issue next window's x loads (regs consumed above); flies under P1/P2/P3
    const int wn = w + npers;
    if (wn < bn) {
      const float4* xv = (const float4*)(x + (size_t)wn * (L * C));
      #pragma unroll
      for (int j = 0; j < 7; ++j) {
        int i = tid + j * 256;
        if (i < L * C / 4) xr[j] = xv[i];
      }
    }
    __syncthreads();

    // ---- P1: QKV = x @ WqkvT + b. Per-wave column ownership (no P1->P2 barrier).
    {
      bf16x8 af[4][4];
      #pragma unroll
      for (int mt = 0; mt < 4; ++mt) {
        int row = mt * 16 + lr; if (row > 48) row = 48;
        #pragma unroll
        for (int kk = 0; kk < 4; ++kk)
          af[mt][kk] = *(const bf16x8*)&xa[row * XP + kk * 32 + lg * 8];
      }
      __syncthreads();   // all waves done reading x before vt overwrites it
      #pragma unroll 2
      for (int ntl = 0; ntl < 6; ++ntl) {
        int nt = (ntl < 2) ? (wv * 2 + ntl)
               : (ntl < 4) ? (8 + wv * 2 + (ntl - 2))
                           : (16 + wv * 2 + (ntl - 4));
        int ncol = nt * 16 + lr;
        const ushort* bp = wqkvT + ncol * C + lg * 8;
        bf16x8 b0 = *(const bf16x8*)(bp);
        bf16x8 b1 = *(const bf16x8*)(bp + 32);
        bf16x8 b2 = *(const bf16x8*)(bp + 64);
        bf16x8 b3 = *(const bf16x8*)(bp + 96);
        float bias = b_qkv[ncol];
        float sc = (ncol < 128) ? 0.5f * LOG2E : 1.0f;
        #pragma unroll
        for (int mt = 0; mt < 4; ++mt) {
          f32x4 acc = {0.f, 0.f, 0.f, 0.f};
          acc = __builtin_amdgcn_mfma_f32_16x16x32_bf16(af[mt][0], b0, acc, 0, 0, 0);
          acc = __builtin_amdgcn_mfma_f32_16x16x32_bf16(af[mt][1], b1, acc, 0, 0, 0);
          acc = __builtin_amdgcn_mfma_f32_16x16x32_bf16(af[mt][2], b2, acc, 0, 0, 0);
          acc = __builtin_amdgcn_mfma_f32_16x16x32_bf16(af[mt][3], b3, acc, 0, 0, 0);
          if (ncol < 256) {
            #pragma unroll
            for (int r = 0; r < 4; ++r) {
              int row = mt * 16 + lg * 4 + r;
              if (row < L) qk[row * QKP + ncol] = bf1((acc[r] + bias) * sc);
            }
          } else {
            int kbase = mt * 16 + lg * 4;
            uint2 pv = make_uint2(pack2(acc[0] + bias, acc[1] + bias),
                                  pack2(acc[2] + bias, acc[3] + bias));
            *(uint2*)&vt[(ncol - 256) * VTP + kbase] = pv;
          }
        }
      }
    }
    // no barrier: P2 inputs are wave-private

    // ---- P2: attention, 8 heads per wave ----
    {
      char* pw = (char*)&p_lds[wv][0];
      const f32x4* bx = (const f32x4*)biasx;
      #pragma unroll 2
      for (int hh = 0; hh < 8; ++hh) {
        int h = wv * 8 + hh;
        f32x4 acc[4][4];
        #pragma unroll
        for (int mt = 0; mt < 4; ++mt)
          #pragma unroll
          for (int nt = 0; nt < 4; ++nt)
            acc[mt][nt] = bx[(h * 16 + mt * 4 + nt) * 64 + l];
        head_body(acc, h, qk, vt, pw, qk, lr, lg);
      }
    }
    __syncthreads();   // P3 reads all columns (cross-wave)

    // ---- P3: out = attn_out @ WprojT + b_proj ----
    {
      bf16x8 pf[4][4];
      #pragma unroll
      for (int mt = 0; mt < 4; ++mt) {
        int row = mt * 16 + lr; if (row > 48) row = 48;
        #pragma unroll
        for (int kk = 0; kk < 4; ++kk)
          pf[mt][kk] = *(const bf16x8*)&qk[row * QKP + kk * 32 + lg * 8];
      }
      float* outw = out + (size_t)w * (L * C);
      #pragma unroll 2
      for (int ntl = 0; ntl < 2; ++ntl) {
        int ncol = (wv * 2 + ntl) * 16 + lr;
        const ushort* bp = wprojT + ncol * C + lg * 8;
        bf16x8 b0 = *(const bf16x8*)(bp);
        bf16x8 b1 = *(const bf16x8*)(bp + 32);
        bf16x8 b2 = *(const bf16x8*)(bp + 64);
        bf16x8 b3 = *(const bf16x8*)(bp + 96);
        float bias = b_proj[ncol];
        #pragma unroll
        for (int mt = 0; mt < 4; ++mt) {
          f32x4 acc = {0.f, 0.f, 0.f, 0.f};
          acc = __builtin_amdgcn_mfma_f32_16x16x32_bf16(pf[mt][0], b0, acc, 0, 0, 0);
          acc = __builtin_amdgcn_mfma_f32_16x16x32_bf16(pf[mt][1], b1, acc, 0, 0, 0);
          acc = __builtin_amdgcn_mfma_f32_16x16x32_bf16(pf[mt][2], b2, acc, 0, 0, 0);
          acc = __builtin_amdgcn_mfma_f32_16x16x32_bf16(pf[mt][3], b3, acc, 0, 0, 0);
          #pragma unroll
          for (int r = 0; r < 4; ++r) {
            int row = mt * 16 + lg * 4 + r;
            if (row < L) outw[row * C + ncol] = acc[r] + bias;
          }
        }
      }
    }
    // next iteration's P0' writes s_xv: safe — the post-P0' barrier orders
    // every wave's P3 (qk reads) before the next P1's qk writes, and P3
    // never touches s_xv.
    w = wn;
  }
}

extern "C" void kernel_launch(void* const* d_in, const int* in_sizes, int n_in,
                              void* d_out, int out_size, void* d_ws, size_t ws_size,
                              hipStream_t stream) {
  const float* x     = (const float*)d_in[0];
  const float* Wqkv  = (const float*)d_in[1];
  const float* bqkv  = (const float*)d_in[2];
  const float* Wproj = (const float*)d_in[3];
  const float* bproj = (const float*)d_in[4];
  const float* btab  = (const float*)d_in[5];
  float* out = (float*)d_out;
  ushort* ws = (ushort*)d_ws;
  float* biasx = (float*)(ws + 65536);   // after 131072 B of bf16 weights

  int bn = in_sizes[0] / (L * C);
  int npers = (bn < NPERS) ? bn : NPERS;

  hipLaunchKernelGGL(prep_weights_kernel, dim3(256), dim3(256), 0, stream,
                     Wqkv, Wproj, ws);
  hipLaunchKernelGGL(prep_bias_kernel, dim3(512), dim3(256), 0, stream,
                     btab, biasx);
  hipLaunchKernelGGL(win_attn_kernel, dim3(npers), dim3(256), 0, stream,
                     x, bqkv, bproj, ws, ws + 49152, biasx, out, bn, npers);
}

// Round 16
// 168.375 us; speedup vs baseline: 1.7920x; 1.7920x over previous
//
#include <hip/hip_runtime.h>
#include <hip/hip_bf16.h>
#include <stdint.h>

#define L 49
#define C 128
#define H 32

typedef __attribute__((ext_vector_type(8))) short bf16x8;
typedef __attribute__((ext_vector_type(4))) float f32x4;

// LDS pitches (elements)
#define XP 136    // x staging pitch (bf16), inside s_xv region
#define VTP 72    // V^T pitch: 144B rows (16B-aligned, 36 dw = 4 mod 32 -> 2-way max)
#define QKP 264   // Q|K pitch: 528B rows (16B-aligned, 132 dw = 4 mod 32 -> 2-way max)

#define LOG2E 1.44269504f

// round-half-up f32->bf16 bit helpers (1 VALU op each) — known-good path
__device__ __forceinline__ uint32_t rbits(float f) {
  return __builtin_bit_cast(uint32_t, f) + 0x8000u;
}
// pack bf16(a) into low u16, bf16(b) into high u16 (one v_perm_b32)
__device__ __forceinline__ uint32_t pack2(float a, float b) {
  return __builtin_amdgcn_perm(rbits(b), rbits(a), 0x07060302u);
}
__device__ __forceinline__ ushort bf1(float a) { return (ushort)(rbits(a) >> 16); }

__device__ __forceinline__ bf16x8 mk_frag(uint2 d, bool valid) {
  union { uint32_t u[4]; bf16x8 v; } r;
  r.u[0] = valid ? d.x : 0u;
  r.u[1] = valid ? d.y : 0u;
  r.u[2] = 0u; r.u[3] = 0u;
  return r.v;
}
__device__ __forceinline__ bf16x8 zero8() {
  union { uint32_t u[4]; bf16x8 v; } r;
  r.u[0] = r.u[1] = r.u[2] = r.u[3] = 0u;
  return r.v;
}
__device__ __forceinline__ bf16x8 ones8() {   // 8 x bf16(1.0)
  union { uint32_t u[4]; bf16x8 v; } r;
  r.u[0] = r.u[1] = r.u[2] = r.u[3] = 0x3F803F80u;
  return r.v;
}

// ---- fused prep: weights transpose+bf16 AND bias expansion (one launch) ----
// i in [0, 49152): W_qkvT[n][k];  [49152, 65536): W_projT;  [65536, 196608): biasx.
// biasx[(((h*16 + mt*4 + nt)*64) + lane)*4 + r], log2-domain, pads = -1e30.
__global__ void __launch_bounds__(256) prep_all_kernel(
    const float* __restrict__ Wqkv, const float* __restrict__ Wproj,
    const float* __restrict__ bt,
    ushort* __restrict__ ws, float* __restrict__ biasx) {
  int i = blockIdx.x * 256 + threadIdx.x;   // 196608 total = 768 x 256
  if (i < 384 * 128) {
    int n = i >> 7, k = i & 127;
    ws[i] = bf1(Wqkv[k * 384 + n]);              // W_qkvT[n][k]
  } else if (i < 65536) {
    int j = i - 49152;
    int n = j >> 7, k = j & 127;
    ws[49152 + j] = bf1(Wproj[k * 128 + n]);     // W_projT[n][k]
  } else {
    int b = i - 65536;                           // 131072 bias-frag elements
    int r = b & 3, lane = (b >> 2) & 63, t = b >> 8;
    int nt = t & 3, mt = (t >> 2) & 3, h = t >> 4;
    int q = nt * 16 + (lane & 15);
    int k = mt * 16 + ((lane >> 4) & 3) * 4 + r;
    float v = -1e30f;
    if (q < L && k < L) {
      int qi = q / 7, qj = q % 7, ki = k / 7, kj = k % 7;
      int idx = (qi - ki + 6) * 13 + (qj - kj + 6);
      v = bt[idx * H + h] * LOG2E;               // log2-domain bias
    }
    biasx[b] = v;
  }
}

// per-head attention body: QK^T MFMA (C preloaded with bias), exp2 softmax,
// P->LDS bf16 swizzled, PV MFMA with ones-channel denominator, O write.
__device__ __forceinline__ void head_body(
    f32x4 (&acc)[4][4], int h, const ushort* qk, const ushort* vt,
    char* pw, ushort* qk_mut, int lr, int lg) {
  // K rows -> A frags, Q rows -> B frags (d=4 in k-slots 0..3 of lane-group 0)
  bf16x8 ka[4], qb[4];
  #pragma unroll
  for (int mt = 0; mt < 4; ++mt) {
    int row = mt * 16 + lr; if (row > 48) row = 48;
    uint2 d = *(const uint2*)&qk[row * QKP + 128 + h * 4];
    ka[mt] = mk_frag(d, lg == 0);
  }
  #pragma unroll
  for (int nt = 0; nt < 4; ++nt) {
    int row = nt * 16 + lr; if (row > 48) row = 48;
    uint2 d = *(const uint2*)&qk[row * QKP + h * 4];
    qb[nt] = mk_frag(d, lg == 0);
  }
  __builtin_amdgcn_s_setprio(1);
  #pragma unroll
  for (int nt = 0; nt < 4; ++nt)
    #pragma unroll
    for (int mt = 0; mt < 4; ++mt)
      acc[mt][nt] = __builtin_amdgcn_mfma_f32_16x16x32_bf16(ka[mt], qb[nt], acc[mt][nt], 0, 0, 0);
  __builtin_amdgcn_s_setprio(0);
  // V^T frags: rows 0..3 = channels, row 4 = ones (den channel), rest zero
  bf16x8 va[2];
  #pragma unroll
  for (int ks = 0; ks < 2; ++ks) {
    bf16x8 t = *(const bf16x8*)&vt[(h * 4 + (lr & 3)) * VTP + ks * 32 + lg * 8];
    va[ks] = (lr < 4) ? t : ((lr == 4) ? ones8() : zero8());
  }
  // per q-tile: exp2 (no max-sub), P->LDS (bf16, swizzled), PV (+den row), O write.
  // mt==3 trim: k = 48+lg*4+r, r>0 is ALWAYS pad (bias -1e30 -> exp2 = 0 ->
  // bf16 bits 0) — emit constants, bit-identical, saves 3 exp2 + 1 perm/q-tile.
  #pragma unroll
  for (int nt = 0; nt < 4; ++nt) {
    #pragma unroll
    for (int mt = 0; mt < 4; ++mt) {
      uint32_t d0, d1;
      if (mt < 3) {
        uint32_t u0 = rbits(__builtin_amdgcn_exp2f(acc[mt][nt][0]));
        uint32_t u1 = rbits(__builtin_amdgcn_exp2f(acc[mt][nt][1]));
        uint32_t u2 = rbits(__builtin_amdgcn_exp2f(acc[mt][nt][2]));
        uint32_t u3 = rbits(__builtin_amdgcn_exp2f(acc[mt][nt][3]));
        d0 = __builtin_amdgcn_perm(u1, u0, 0x07060302u);
        d1 = __builtin_amdgcn_perm(u3, u2, 0x07060302u);
      } else {
        float e0 = __builtin_amdgcn_exp2f(acc[mt][nt][0]);  // k=48 (valid for lg==0)
        d0 = pack2(e0, 0.0f);   // hi half = bf16(0), folded constant
        d1 = 0u;                // k=50..51 pad -> bf16 zeros
      }
      int byte = lr * 128 + mt * 32 + lg * 8;
      byte ^= (lr & 7) << 4;
      *(uint2*)(pw + byte) = make_uint2(d0, d1);
    }
    f32x4 oo = {0.f, 0.f, 0.f, 0.f};
    __builtin_amdgcn_s_setprio(1);
    #pragma unroll
    for (int ks = 0; ks < 2; ++ks) {
      int byte = lr * 128 + ks * 64 + lg * 16;
      byte ^= (lr & 7) << 4;
      bf16x8 pb = *(const bf16x8*)(pw + byte);
      oo = __builtin_amdgcn_mfma_f32_16x16x32_bf16(va[ks], pb, oo, 0, 0, 0);
    }
    __builtin_amdgcn_s_setprio(0);
    // den = D row 4 (ones channel) lives in lg==1 lanes' oo[0]
    float den = __shfl_xor(oo[0], 16);
    if (lg == 0) {
      float iv = __builtin_amdgcn_rcpf(den);
      int q = nt * 16 + lr;
      if (q < L) {
        uint2 od = make_uint2(pack2(oo[0] * iv, oo[1] * iv),
                              pack2(oo[2] * iv, oo[3] * iv));
        *(uint2*)&qk_mut[q * QKP + h * 4] = od;   // into consumed Q slice (wave-private)
      }
    }
  }
}

__global__ void __launch_bounds__(256, 3) win_attn_kernel(
    const float* __restrict__ x,
    const float* __restrict__ b_qkv,
    const float* __restrict__ b_proj,
    const ushort* __restrict__ wqkvT,
    const ushort* __restrict__ wprojT,
    const float* __restrict__ biasx,
    float* __restrict__ out) {
  // s_xv: x staging (49*136=6664 el) ALIASED with V^T (128*72=9216 el).
  // Safe: x fully consumed into af registers before vt is written (barrier).
  __shared__ alignas(16) ushort s_xv[C * VTP];       // 18432 B
  __shared__ alignas(16) ushort qk[L * QKP];         // 25872 B: Q(0:128)|K(128:256)
  __shared__ alignas(16) ushort p_lds[4][16 * 64];   //  8192 B: per-wave P, XOR-swizzled
  // total 52496 B -> 3 blocks/CU

  ushort* xa = s_xv;   // pitch XP (x staging)
  ushort* vt = s_xv;   // pitch VTP (V^T)

  const int tid = threadIdx.x;
  const int w = blockIdx.x;
  const int wv = tid >> 6;
  const int l = tid & 63;
  const int lr = l & 15;
  const int lg = l >> 4;

  // ---- P0: stage x as bf16 ----
  {
    const float4* xv = (const float4*)(x + (size_t)w * (L * C));
    for (int i = tid; i < L * C / 4; i += 256) {
      float4 v = xv[i];
      int e = i * 4;
      int r = e >> 7, c = e & 127;
      uint2 u = make_uint2(pack2(v.x, v.y), pack2(v.z, v.w));
      *(uint2*)&xa[r * XP + c] = u;
    }
  }
  __syncthreads();

  // ---- P1: QKV = x @ WqkvT + b (MFMA). Q scaled by 0.5*log2e; V -> vt (aliased).
  //      PER-WAVE COLUMN OWNERSHIP: wave wv computes exactly the Q/K/V tiles its
  //      own P2 heads consume -> no barrier between P1 and P2 (same-wave DS order).
  {
    bf16x8 af[4][4];
    #pragma unroll
    for (int mt = 0; mt < 4; ++mt) {
      int row = mt * 16 + lr; if (row > 48) row = 48;
      #pragma unroll
      for (int kk = 0; kk < 4; ++kk)
        af[mt][kk] = *(const bf16x8*)&xa[row * XP + kk * 32 + lg * 8];
    }
    __syncthreads();   // all waves done reading x before vt overwrites it
    #pragma unroll 2
    for (int ntl = 0; ntl < 6; ++ntl) {
      // tiles: Q {2wv, 2wv+1}, K {8+2wv, 8+2wv+1}, V {16+2wv, 16+2wv+1}
      int nt = (ntl < 2) ? (wv * 2 + ntl)
             : (ntl < 4) ? (8 + wv * 2 + (ntl - 2))
                         : (16 + wv * 2 + (ntl - 4));
      int ncol = nt * 16 + lr;
      const ushort* bp = wqkvT + ncol * C + lg * 8;
      bf16x8 b0 = *(const bf16x8*)(bp);
      bf16x8 b1 = *(const bf16x8*)(bp + 32);
      bf16x8 b2 = *(const bf16x8*)(bp + 64);
      bf16x8 b3 = *(const bf16x8*)(bp + 96);
      float bias = b_qkv[ncol];
      float sc = (ncol < 128) ? 0.5f * LOG2E : 1.0f;   // Q pre-scaled into log2 domain
      #pragma unroll
      for (int mt = 0; mt < 4; ++mt) {
        f32x4 acc = {0.f, 0.f, 0.f, 0.f};
        acc = __builtin_amdgcn_mfma_f32_16x16x32_bf16(af[mt][0], b0, acc, 0, 0, 0);
        acc = __builtin_amdgcn_mfma_f32_16x16x32_bf16(af[mt][1], b1, acc, 0, 0, 0);
        acc = __builtin_amdgcn_mfma_f32_16x16x32_bf16(af[mt][2], b2, acc, 0, 0, 0);
        acc = __builtin_amdgcn_mfma_f32_16x16x32_bf16(af[mt][3], b3, acc, 0, 0, 0);
        if (ncol < 256) {            // Q or K -> qk rows
          #pragma unroll
          for (int r = 0; r < 4; ++r) {
            int row = mt * 16 + lg * 4 + r;
            if (row < L) qk[row * QKP + ncol] = bf1((acc[r] + bias) * sc);
          }
        } else {                     // V -> vt[c][k], 4 consecutive k packed
          int kbase = mt * 16 + lg * 4;
          uint2 pv = make_uint2(pack2(acc[0] + bias, acc[1] + bias),
                                pack2(acc[2] + bias, acc[3] + bias));
          *(uint2*)&vt[(ncol - 256) * VTP + kbase] = pv;
        }
      }
    }
  }
  // NO __syncthreads here: each wave's P2 inputs were produced by itself.

  // ---- P2: attention (single acc buffer; compiler-managed overlap via unroll 2) ----
  // attn-out written into this wave's private (consumed) Q-column slice of qk.
  {
    char* pw = (char*)&p_lds[wv][0];
    const f32x4* bx = (const f32x4*)biasx;
    #pragma unroll 2
    for (int hh = 0; hh < 8; ++hh) {
      int h = wv * 8 + hh;
      // C init = expanded bias (pads = -1e30 -> masking for free)
      f32x4 acc[4][4];
      #pragma unroll
      for (int mt = 0; mt < 4; ++mt)
        #pragma unroll
        for (int nt = 0; nt < 4; ++nt)
          acc[mt][nt] = bx[(h * 16 + mt * 4 + nt) * 64 + l];
      head_body(acc, h, qk, vt, pw, qk, lr, lg);
    }
  }
  __syncthreads();   // P3 reads all columns (cross-wave)

  // ---- P3: out = attn_out @ WprojT + b_proj (f32 stores); attn_out lives in qk[:,0:128] ----
  {
    bf16x8 pf[4][4];
    #pragma unroll
    for (int mt = 0; mt < 4; ++mt) {
      int row = mt * 16 + lr; if (row > 48) row = 48;
      #pragma unroll
      for (int kk = 0; kk < 4; ++kk)
        pf[mt][kk] = *(const bf16x8*)&qk[row * QKP + kk * 32 + lg * 8];
    }
    float* outw = out + (size_t)w * (L * C);
    #pragma unroll 2
    for (int ntl = 0; ntl < 2; ++ntl) {
      int ncol = (wv * 2 + ntl) * 16 + lr;
      const ushort* bp = wprojT + ncol * C + lg * 8;
      bf16x8 b0 = *(const bf16x8*)(bp);
      bf16x8 b1 = *(const bf16x8*)(bp + 32);
      bf16x8 b2 = *(const bf16x8*)(bp + 64);
      bf16x8 b3 = *(const bf16x8*)(bp + 96);
      float bias = b_proj[ncol];
      #pragma unroll
      for (int mt = 0; mt < 4; ++mt) {
        f32x4 acc = {0.f, 0.f, 0.f, 0.f};
        acc = __builtin_amdgcn_mfma_f32_16x16x32_bf16(pf[mt][0], b0, acc, 0, 0, 0);
        acc = __builtin_amdgcn_mfma_f32_16x16x32_bf16(pf[mt][1], b1, acc, 0, 0, 0);
        acc = __builtin_amdgcn_mfma_f32_16x16x32_bf16(pf[mt][2], b2, acc, 0, 0, 0);
        acc = __builtin_amdgcn_mfma_f32_16x16x32_bf16(pf[mt][3], b3, acc, 0, 0, 0);
        #pragma unroll
        for (int r = 0; r < 4; ++r) {
          int row = mt * 16 + lg * 4 + r;
          if (row < L) outw[row * C + ncol] = acc[r] + bias;
        }
      }
    }
  }
}

extern "C" void kernel_launch(void* const* d_in, const int* in_sizes, int n_in,
                              void* d_out, int out_size, void* d_ws, size_t ws_size,
                              hipStream_t stream) {
  const float* x     = (const float*)d_in[0];
  const float* Wqkv  = (const float*)d_in[1];
  const float* bqkv  = (const float*)d_in[2];
  const float* Wproj = (const float*)d_in[3];
  const float* bproj = (const float*)d_in[4];
  const float* btab  = (const float*)d_in[5];
  float* out = (float*)d_out;
  ushort* ws = (ushort*)d_ws;
  float* biasx = (float*)(ws + 65536);   // after 131072 B of bf16 weights

  int bn = in_sizes[0] / (L * C);

  hipLaunchKernelGGL(prep_all_kernel, dim3(768), dim3(256), 0, stream,
                     Wqkv, Wproj, btab, ws, biasx);
  hipLaunchKernelGGL(win_attn_kernel, dim3(bn), dim3(256), 0, stream,
                     x, bqkv, bproj, ws, ws + 49152, biasx, out);
}